// Round 3
// baseline (1204.999 us; speedup 1.0000x reference)
//
#include <hip/hip_runtime.h>

#define N_TOK 8192
#define CDIM  1024
#define HDIM  4096
#define NEXP  8
#define TOPK  2
#define ROWS  (N_TOK*TOPK)

#define BM 128
#define BN 128
#define BK 64
#define LDK 72   // padded LDS k-stride (shorts): 2-way bank aliasing only (free per m136)

typedef short short8 __attribute__((ext_vector_type(8)));
typedef float floatx4 __attribute__((ext_vector_type(4)));

__device__ __forceinline__ unsigned short f2bf(float f){
  union { float f; unsigned int u; } v; v.f = f;
  unsigned int u = v.u;
  return (unsigned short)((u + 0x7fffu + ((u >> 16) & 1u)) >> 16);
}

// tanh-GELU (jax.nn.gelu approximate=True) rewritten as x * sigmoid(2u)
__device__ __forceinline__ float gelu_tanh(float x){
  float u = 0.7978845608028654f * (x + 0.044715f * x * x * x);
  float s = __fdividef(1.f, 1.f + __expf(-2.f * u));
  return x * s;
}

// ---- slice transpose + fp32->bf16 cast:
// dst_bf16[e][c*RP + r] = (bf16) src_f32[e][(roff+r)*lds_ + coff + c],  r<RP, c<CP
__global__ void transpose_cast(const float* __restrict__ src,
                               unsigned short* __restrict__ dst,
                               int roff, int RP, int lds_, int coff, int CP,
                               size_t srcEsz){
  __shared__ __align__(16) unsigned short tile[64][72];
  const int e = blockIdx.z;
  const float* s = src + (size_t)e * srcEsz;
  unsigned short* d = dst + (size_t)e * (size_t)RP * (size_t)CP;
  const int c0 = blockIdx.x * 64, r0 = blockIdx.y * 64;
  const int tid = threadIdx.x;
  #pragma unroll
  for (int i = 0; i < 2; i++){
    int r  = (tid >> 3) + i * 32;
    int cc = (tid & 7) * 8;
    const float* p = s + (size_t)(roff + r0 + r) * lds_ + coff + c0 + cc;
    float4 v0 = *(const float4*)p;
    float4 v1 = *(const float4*)(p + 4);
    unsigned short t8[8];
    t8[0]=f2bf(v0.x); t8[1]=f2bf(v0.y); t8[2]=f2bf(v0.z); t8[3]=f2bf(v0.w);
    t8[4]=f2bf(v1.x); t8[5]=f2bf(v1.y); t8[6]=f2bf(v1.z); t8[7]=f2bf(v1.w);
    *(uint4*)&tile[r][cc] = *(uint4*)t8;
  }
  __syncthreads();
  #pragma unroll
  for (int i = 0; i < 2; i++){
    int oc = (tid >> 3) + i * 32;   // tile col = output row index (c)
    int rr = (tid & 7) * 8;         // tile row base = output col chunk (r)
    unsigned short tmp[8];
    #pragma unroll
    for (int j = 0; j < 8; j++) tmp[j] = tile[rr + j][oc];
    *(uint4*)(d + (size_t)(c0 + oc) * RP + r0 + rr) = *(uint4*)tmp;
  }
}

// ---------------- router: one wave per token (fp32 in) ----------------
__global__ void router_topk(const float* __restrict__ x,
                            const float* __restrict__ Wr,
                            int* __restrict__ cnt,
                            int* __restrict__ top_e,
                            float* __restrict__ top_g){
  const int lane = threadIdx.x & 63;
  const int wv   = threadIdx.x >> 6;
  const int t    = blockIdx.x * 4 + wv;
  const float* xr = x + (size_t)t * CDIM;
  float p[NEXP];
  #pragma unroll
  for (int e = 0; e < NEXP; e++) p[e] = 0.f;
  for (int c = lane; c < CDIM; c += 64){
    float xv = xr[c];
    float4 w0 = *(const float4*)(Wr + c * NEXP);
    float4 w1 = *(const float4*)(Wr + c * NEXP + 4);
    p[0] = fmaf(xv, w0.x, p[0]); p[1] = fmaf(xv, w0.y, p[1]);
    p[2] = fmaf(xv, w0.z, p[2]); p[3] = fmaf(xv, w0.w, p[3]);
    p[4] = fmaf(xv, w1.x, p[4]); p[5] = fmaf(xv, w1.y, p[5]);
    p[6] = fmaf(xv, w1.z, p[6]); p[7] = fmaf(xv, w1.w, p[7]);
  }
  #pragma unroll
  for (int e = 0; e < NEXP; e++){
    #pragma unroll
    for (int off = 32; off > 0; off >>= 1)
      p[e] += __shfl_xor(p[e], off, 64);
  }
  if (lane == 0){
    int e0 = 0; float v0 = p[0];
    #pragma unroll
    for (int e = 1; e < NEXP; e++) if (p[e] > v0){ v0 = p[e]; e0 = e; }
    int e1 = -1; float v1 = -1e30f;
    #pragma unroll
    for (int e = 0; e < NEXP; e++) if (e != e0 && p[e] > v1){ v1 = p[e]; e1 = e; }
    float ex  = __expf(v1 - v0);
    float inv = 1.f / (1.f + ex);
    top_e[t * 2 + 0] = e0; top_e[t * 2 + 1] = e1;
    top_g[t * 2 + 0] = inv; top_g[t * 2 + 1] = ex * inv;
    atomicAdd(&cnt[e0], 1);
    atomicAdd(&cnt[e1], 1);
  }
}

__global__ void scan_offsets(const int* __restrict__ cnt,
                             int* __restrict__ off,
                             int* __restrict__ cursor){
  if (threadIdx.x == 0){
    int s = 0;
    for (int e = 0; e < NEXP; e++){ off[e] = s; s += cnt[e]; cursor[e] = 0; }
  }
}

__global__ void assign_rows(const int* __restrict__ off, int* __restrict__ cursor,
                            const int* __restrict__ top_e, const float* __restrict__ top_g,
                            int* __restrict__ tok_of_row, float* __restrict__ gate_of_row){
  int t = blockIdx.x * blockDim.x + threadIdx.x;
  if (t >= N_TOK) return;
  #pragma unroll
  for (int k = 0; k < TOPK; k++){
    int e = top_e[t * 2 + k];
    int pos = atomicAdd(&cursor[e], 1);
    int r = off[e] + pos;
    tok_of_row[r]  = t;
    gate_of_row[r] = top_g[t * 2 + k];
  }
}

// ---- GEMM1: hbuf(:, Hslice) = gelu(x_gathered(f32->bf16) @ w1t_slice^T), K=CDIM ----
__global__ __launch_bounds__(256, 2)
void gemm1_expert(const float* __restrict__ x,               // (N_TOK, C) fp32
                  const unsigned short* __restrict__ w1t,    // (E, HP, C) bf16
                  const int* __restrict__ cnt, const int* __restrict__ off,
                  const int* __restrict__ tok_of_row,
                  unsigned short* __restrict__ hbuf,         // (ROWS, HP) bf16
                  int HP){
  const int e  = blockIdx.z;
  const int m  = cnt[e];
  const int mt = blockIdx.y;
  if (mt * BM >= m) return;
  const int nt   = blockIdx.x;
  const int base = off[e];

  __shared__ __align__(16) unsigned short As[BM * LDK];
  __shared__ __align__(16) unsigned short Bs[BN * LDK];

  const int tid = threadIdx.x;
  const int lane = tid & 63, wv = tid >> 6;
  const int wm = wv & 1, wn = wv >> 1;
  const int q = lane >> 4, l16 = lane & 15;

  floatx4 acc[4][4];
  #pragma unroll
  for (int i = 0; i < 4; i++)
    #pragma unroll
    for (int j = 0; j < 4; j++) acc[i][j] = (floatx4){0.f, 0.f, 0.f, 0.f};

  const unsigned short* bsrc = w1t + ((size_t)e * HP + (size_t)nt * BN) * CDIM;

  int tokr[4];
  #pragma unroll
  for (int i = 0; i < 4; i++){
    int row  = (tid + i * 256) >> 3;
    int grow = mt * BM + row;
    tokr[i] = tok_of_row[base + (grow < m ? grow : 0)];
  }

  for (int kb = 0; kb < CDIM; kb += BK){
    #pragma unroll
    for (int i = 0; i < 4; i++){
      int chunk = tid + i * 256;
      int row = chunk >> 3;
      int kc  = (chunk & 7) * 8;
      const float* p = x + (size_t)tokr[i] * CDIM + kb + kc;
      float4 v0 = *(const float4*)p;
      float4 v1 = *(const float4*)(p + 4);
      unsigned short t8[8];
      t8[0]=f2bf(v0.x); t8[1]=f2bf(v0.y); t8[2]=f2bf(v0.z); t8[3]=f2bf(v0.w);
      t8[4]=f2bf(v1.x); t8[5]=f2bf(v1.y); t8[6]=f2bf(v1.z); t8[7]=f2bf(v1.w);
      *(uint4*)&As[row * LDK + kc] = *(uint4*)t8;
    }
    #pragma unroll
    for (int i = 0; i < 4; i++){
      int chunk = tid + i * 256;
      int row = chunk >> 3;
      int kc  = (chunk & 7) * 8;
      uint4 v = *(const uint4*)(bsrc + (size_t)row * CDIM + kb + kc);
      *(uint4*)&Bs[row * LDK + kc] = v;
    }
    __syncthreads();
    #pragma unroll
    for (int ks = 0; ks < BK; ks += 32){
      short8 a[4], b[4];
      #pragma unroll
      for (int i = 0; i < 4; i++)
        a[i] = *(const short8*)&As[(wm * 64 + i * 16 + l16) * LDK + ks + q * 8];
      #pragma unroll
      for (int j = 0; j < 4; j++)
        b[j] = *(const short8*)&Bs[(wn * 64 + j * 16 + l16) * LDK + ks + q * 8];
      #pragma unroll
      for (int i = 0; i < 4; i++)
        #pragma unroll
        for (int j = 0; j < 4; j++)
          acc[i][j] = __builtin_amdgcn_mfma_f32_16x16x32_bf16(a[i], b[j], acc[i][j], 0, 0, 0);
    }
    __syncthreads();
  }

  #pragma unroll
  for (int i = 0; i < 4; i++){
    #pragma unroll
    for (int r = 0; r < 4; r++){
      int row  = wm * 64 + i * 16 + q * 4 + r;
      int grow = mt * BM + row;
      if (grow < m){
        size_t hrow = (size_t)(base + grow) * HP + (size_t)nt * BN;
        #pragma unroll
        for (int j = 0; j < 4; j++){
          float g = gelu_tanh(acc[i][j][r]);
          hbuf[hrow + wn * 64 + j * 16 + l16] = f2bf(g);
        }
      }
    }
  }
}

// ---- GEMM2: d_out[token] += gate * (hbuf_slice @ w2t_slice^T), K = HP, fp32 atomics ----
__global__ __launch_bounds__(256, 2)
void gemm2_expert(const unsigned short* __restrict__ hbuf,   // (ROWS, HP) bf16
                  const unsigned short* __restrict__ w2t,    // (E, C, HP) bf16
                  const int* __restrict__ cnt, const int* __restrict__ off,
                  const int* __restrict__ tok_of_row, const float* __restrict__ gate_of_row,
                  float* __restrict__ out,                   // (N_TOK, C) fp32
                  int HP){
  const int e  = blockIdx.z;
  const int m  = cnt[e];
  const int mt = blockIdx.y;
  if (mt * BM >= m) return;
  const int nt   = blockIdx.x;
  const int base = off[e];

  __shared__ __align__(16) unsigned short As[BM * LDK];
  __shared__ __align__(16) unsigned short Bs[BN * LDK];

  const int tid = threadIdx.x;
  const int lane = tid & 63, wv = tid >> 6;
  const int wm = wv & 1, wn = wv >> 1;
  const int q = lane >> 4, l16 = lane & 15;

  floatx4 acc[4][4];
  #pragma unroll
  for (int i = 0; i < 4; i++)
    #pragma unroll
    for (int j = 0; j < 4; j++) acc[i][j] = (floatx4){0.f, 0.f, 0.f, 0.f};

  const unsigned short* bsrc = w2t + ((size_t)e * CDIM + (size_t)nt * BN) * HP;

  int arow[4];
  #pragma unroll
  for (int i = 0; i < 4; i++){
    int row  = (tid + i * 256) >> 3;
    int grow = mt * BM + row;
    arow[i] = base + (grow < m ? grow : 0);
  }

  for (int kb = 0; kb < HP; kb += BK){
    #pragma unroll
    for (int i = 0; i < 4; i++){
      int chunk = tid + i * 256;
      int row = chunk >> 3;
      int kc  = (chunk & 7) * 8;
      uint4 v = *(const uint4*)(hbuf + (size_t)arow[i] * HP + kb + kc);
      *(uint4*)&As[row * LDK + kc] = v;
    }
    #pragma unroll
    for (int i = 0; i < 4; i++){
      int chunk = tid + i * 256;
      int row = chunk >> 3;
      int kc  = (chunk & 7) * 8;
      uint4 v = *(const uint4*)(bsrc + (size_t)row * HP + kb + kc);
      *(uint4*)&Bs[row * LDK + kc] = v;
    }
    __syncthreads();
    #pragma unroll
    for (int ks = 0; ks < BK; ks += 32){
      short8 a[4], b[4];
      #pragma unroll
      for (int i = 0; i < 4; i++)
        a[i] = *(const short8*)&As[(wm * 64 + i * 16 + l16) * LDK + ks + q * 8];
      #pragma unroll
      for (int j = 0; j < 4; j++)
        b[j] = *(const short8*)&Bs[(wn * 64 + j * 16 + l16) * LDK + ks + q * 8];
      #pragma unroll
      for (int i = 0; i < 4; i++)
        #pragma unroll
        for (int j = 0; j < 4; j++)
          acc[i][j] = __builtin_amdgcn_mfma_f32_16x16x32_bf16(a[i], b[j], acc[i][j], 0, 0, 0);
    }
    __syncthreads();
  }

  #pragma unroll
  for (int i = 0; i < 4; i++){
    #pragma unroll
    for (int r = 0; r < 4; r++){
      int row  = wm * 64 + i * 16 + q * 4 + r;
      int grow = mt * BM + row;
      if (grow < m){
        int gr = base + grow;
        int tok = tok_of_row[gr];
        float gate = gate_of_row[gr];
        float* orow = out + (size_t)tok * CDIM + (size_t)nt * BN;
        #pragma unroll
        for (int j = 0; j < 4; j++)
          atomicAdd(&orow[wn * 64 + j * 16 + l16], acc[i][j][r] * gate);
      }
    }
  }
}

extern "C" void kernel_launch(void* const* d_in, const int* in_sizes, int n_in,
                              void* d_out, int out_size, void* d_ws, size_t ws_size,
                              hipStream_t stream) {
  const float* x  = (const float*)d_in[0];
  const float* Wr = (const float*)d_in[1];
  const float* W1 = (const float*)d_in[2];
  const float* W2 = (const float*)d_in[3];
  float* out = (float*)d_out;

  // output is the fp32 accumulator: zero it (harness poisons it before timed runs)
  hipMemsetAsync(out, 0, (size_t)N_TOK * CDIM * sizeof(float), stream);

  // ---- ws layout: meta (1 MB) + hbuf slice + weight slice; pick smallest P that fits ----
  const size_t META_SZ = 1u << 20;
  int P = -1;
  for (int cand = 1; cand <= 32; cand <<= 1){
    int HPc = HDIM / cand;
    size_t need = META_SZ
                + (size_t)ROWS * HPc * 2                 // hbuf slice (bf16)
                + (size_t)NEXP * HPc * CDIM * 2;         // weight slice (bf16)
    if (need <= ws_size){ P = cand; break; }
  }
  if (P < 0){
    // ws too small for any plan: leave zeros (diagnostic, no crash)
    return;
  }
  const int HP = HDIM / P;

  char* ws = (char*)d_ws;
  int*   cnt         = (int*)ws;                         // 8
  int*   off         = cnt + 8;                          // 8
  int*   cursor      = off + 8;                          // 8
  int*   tok_of_row  = (int*)(ws + 1024);                // ROWS ints
  float* gate_of_row = (float*)(ws + 1024 + 65536);      // ROWS floats
  int*   top_e       = (int*)(ws + 1024 + 131072);       // ROWS ints
  float* top_g       = (float*)(ws + 1024 + 196608);     // ROWS floats

  unsigned short* hbuf = (unsigned short*)(ws + META_SZ);
  unsigned short* wreg = (unsigned short*)(ws + META_SZ + (size_t)ROWS * HP * 2);

  hipMemsetAsync(cnt, 0, 96, stream);

  router_topk<<<dim3(N_TOK/4), 256, 0, stream>>>(x, Wr, cnt, top_e, top_g);
  scan_offsets<<<1, 64, 0, stream>>>(cnt, off, cursor);
  assign_rows<<<dim3(N_TOK/256), 256, 0, stream>>>(off, cursor, top_e, top_g,
                                                   tok_of_row, gate_of_row);

  for (int p = 0; p < P; p++){
    const int h0 = p * HP;
    // W1 slice (E, C, Hslice) -> wreg (E, HP, C), cast bf16
    transpose_cast<<<dim3(HP/64, CDIM/64, NEXP), 256, 0, stream>>>(
        W1, wreg, /*roff=*/0, /*RP=*/CDIM, /*lds_=*/HDIM, /*coff=*/h0, /*CP=*/HP,
        (size_t)CDIM * HDIM);
    gemm1_expert<<<dim3(HP/BN, ROWS/BM, NEXP), 256, 0, stream>>>(
        x, wreg, cnt, off, tok_of_row, hbuf, HP);
    // W2 slice (E, Hslice, C) -> wreg (E, C, HP), cast bf16  (reuses wreg after gemm1)
    transpose_cast<<<dim3(CDIM/64, HP/64, NEXP), 256, 0, stream>>>(
        W2, wreg, /*roff=*/h0, /*RP=*/HP, /*lds_=*/CDIM, /*coff=*/0, /*CP=*/CDIM,
        (size_t)HDIM * CDIM);
    gemm2_expert<<<dim3(CDIM/BN, ROWS/BM, NEXP), 256, 0, stream>>>(
        hbuf, wreg, cnt, off, tok_of_row, gate_of_row, out, HP);
  }
}

// Round 4
// 1008.115 us; speedup vs baseline: 1.1953x; 1.1953x over previous
//
#include <hip/hip_runtime.h>

#define N_TOK 8192
#define CDIM  1024
#define HDIM  4096
#define NEXP  8
#define TOPK  2
#define ROWS  (N_TOK*TOPK)

#define BM 128
#define BN 128
#define BK 64   // shorts; 128 B per LDS row, unpadded (global_load_lds needs lane-order dest)

typedef short short8 __attribute__((ext_vector_type(8)));
typedef float floatx4 __attribute__((ext_vector_type(4)));

typedef __attribute__((address_space(3))) unsigned int       as3_u32;
typedef __attribute__((address_space(1))) const unsigned int as1_u32;

__device__ __forceinline__ void gld16(const unsigned short* g, unsigned short* l){
  // async global->LDS DMA, 16 B/lane; LDS dest = wave-uniform base + lane*16
  __builtin_amdgcn_global_load_lds((as1_u32*)g, (as3_u32*)l, 16, 0, 0);
}

__device__ __forceinline__ unsigned short f2bf(float f){
  union { float f; unsigned int u; } v; v.f = f;
  unsigned int u = v.u;
  return (unsigned short)((u + 0x7fffu + ((u >> 16) & 1u)) >> 16);
}

// tanh-GELU (jax.nn.gelu approximate=True) rewritten as x * sigmoid(2u)
__device__ __forceinline__ float gelu_tanh(float x){
  float u = 0.7978845608028654f * (x + 0.044715f * x * x * x);
  float s = __fdividef(1.f, 1.f + __expf(-2.f * u));
  return x * s;
}

// ---- x fp32 -> bf16 cast (one-shot) ----
__global__ void cast_x(const float4* __restrict__ in, uint2* __restrict__ out){
  int i = blockIdx.x * 256 + threadIdx.x;
  float4 v = in[i];
  unsigned short t[4];
  t[0] = f2bf(v.x); t[1] = f2bf(v.y); t[2] = f2bf(v.z); t[3] = f2bf(v.w);
  out[i] = *(uint2*)t;
}

// ---- slice transpose + fp32->bf16 cast:
// dst_bf16[e][c*RP + r] = (bf16) src_f32[e][(roff+r)*lds_ + coff + c],  r<RP, c<CP
__global__ void transpose_cast(const float* __restrict__ src,
                               unsigned short* __restrict__ dst,
                               int roff, int RP, int lds_, int coff, int CP,
                               size_t srcEsz){
  __shared__ __align__(16) unsigned short tile[64][72];
  const int e = blockIdx.z;
  const float* s = src + (size_t)e * srcEsz;
  unsigned short* d = dst + (size_t)e * (size_t)RP * (size_t)CP;
  const int c0 = blockIdx.x * 64, r0 = blockIdx.y * 64;
  const int tid = threadIdx.x;
  #pragma unroll
  for (int i = 0; i < 2; i++){
    int r  = (tid >> 3) + i * 32;
    int cc = (tid & 7) * 8;
    const float* p = s + (size_t)(roff + r0 + r) * lds_ + coff + c0 + cc;
    float4 v0 = *(const float4*)p;
    float4 v1 = *(const float4*)(p + 4);
    unsigned short t8[8];
    t8[0]=f2bf(v0.x); t8[1]=f2bf(v0.y); t8[2]=f2bf(v0.z); t8[3]=f2bf(v0.w);
    t8[4]=f2bf(v1.x); t8[5]=f2bf(v1.y); t8[6]=f2bf(v1.z); t8[7]=f2bf(v1.w);
    *(uint4*)&tile[r][cc] = *(uint4*)t8;
  }
  __syncthreads();
  #pragma unroll
  for (int i = 0; i < 2; i++){
    int oc = (tid >> 3) + i * 32;
    int rr = (tid & 7) * 8;
    unsigned short tmp[8];
    #pragma unroll
    for (int j = 0; j < 8; j++) tmp[j] = tile[rr + j][oc];
    *(uint4*)(d + (size_t)(c0 + oc) * RP + r0 + rr) = *(uint4*)tmp;
  }
}

// ---------------- router: one wave per token (fp32 in) ----------------
__global__ void router_topk(const float* __restrict__ x,
                            const float* __restrict__ Wr,
                            int* __restrict__ cnt,
                            int* __restrict__ top_e,
                            float* __restrict__ top_g){
  const int lane = threadIdx.x & 63;
  const int wv   = threadIdx.x >> 6;
  const int t    = blockIdx.x * 4 + wv;
  const float* xr = x + (size_t)t * CDIM;
  float p[NEXP];
  #pragma unroll
  for (int e = 0; e < NEXP; e++) p[e] = 0.f;
  for (int c = lane; c < CDIM; c += 64){
    float xv = xr[c];
    float4 w0 = *(const float4*)(Wr + c * NEXP);
    float4 w1 = *(const float4*)(Wr + c * NEXP + 4);
    p[0] = fmaf(xv, w0.x, p[0]); p[1] = fmaf(xv, w0.y, p[1]);
    p[2] = fmaf(xv, w0.z, p[2]); p[3] = fmaf(xv, w0.w, p[3]);
    p[4] = fmaf(xv, w1.x, p[4]); p[5] = fmaf(xv, w1.y, p[5]);
    p[6] = fmaf(xv, w1.z, p[6]); p[7] = fmaf(xv, w1.w, p[7]);
  }
  #pragma unroll
  for (int e = 0; e < NEXP; e++){
    #pragma unroll
    for (int off = 32; off > 0; off >>= 1)
      p[e] += __shfl_xor(p[e], off, 64);
  }
  if (lane == 0){
    int e0 = 0; float v0 = p[0];
    #pragma unroll
    for (int e = 1; e < NEXP; e++) if (p[e] > v0){ v0 = p[e]; e0 = e; }
    int e1 = -1; float v1 = -1e30f;
    #pragma unroll
    for (int e = 0; e < NEXP; e++) if (e != e0 && p[e] > v1){ v1 = p[e]; e1 = e; }
    float ex  = __expf(v1 - v0);
    float inv = 1.f / (1.f + ex);
    top_e[t * 2 + 0] = e0; top_e[t * 2 + 1] = e1;
    top_g[t * 2 + 0] = inv; top_g[t * 2 + 1] = ex * inv;
    atomicAdd(&cnt[e0], 1);
    atomicAdd(&cnt[e1], 1);
  }
}

__global__ void scan_offsets(const int* __restrict__ cnt,
                             int* __restrict__ off,
                             int* __restrict__ cursor){
  if (threadIdx.x == 0){
    int s = 0;
    for (int e = 0; e < NEXP; e++){ off[e] = s; s += cnt[e]; cursor[e] = 0; }
  }
}

__global__ void assign_rows(const int* __restrict__ off, int* __restrict__ cursor,
                            const int* __restrict__ top_e, const float* __restrict__ top_g,
                            int* __restrict__ tok_of_row, float* __restrict__ gate_of_row){
  int t = blockIdx.x * blockDim.x + threadIdx.x;
  if (t >= N_TOK) return;
  #pragma unroll
  for (int k = 0; k < TOPK; k++){
    int e = top_e[t * 2 + k];
    int pos = atomicAdd(&cursor[e], 1);
    int r = off[e] + pos;
    tok_of_row[r]  = t;
    gate_of_row[r] = top_g[t * 2 + k];
  }
}

// ---- GEMM1: hbuf(:, Hslice) = gelu(xbf_gathered @ w1t_slice^T), K=CDIM ----
__global__ __launch_bounds__(256, 2)
void gemm1_expert(const unsigned short* __restrict__ xbf,    // (N_TOK, C) bf16
                  const unsigned short* __restrict__ w1t,    // (E, HP, C) bf16
                  const int* __restrict__ cnt, const int* __restrict__ off,
                  const int* __restrict__ tok_of_row,
                  unsigned short* __restrict__ hbuf,         // (ROWS, HP) bf16
                  int HP){
  const int e  = blockIdx.z;
  const int m  = cnt[e];
  const int mt = blockIdx.y;
  if (mt * BM >= m) return;
  const int nt   = blockIdx.x;
  const int base = off[e];

  __shared__ __align__(16) unsigned short As[BM * BK];
  __shared__ __align__(16) unsigned short Bs[BN * BK];

  const int tid = threadIdx.x;
  const int lane = tid & 63, w = tid >> 6;
  const int wm = w & 1, wn = w >> 1;
  const int q = lane >> 4, l16 = lane & 15;
  const int sw = l16 & 7;                       // XOR swizzle key for frag reads

  const unsigned short* bsrc = w1t + ((size_t)e * HP + (size_t)nt * BN) * CDIM;

  // staging addresses: wave w stages A rows [w*32, w*32+32) and B rows likewise,
  // 8 rows per issue; lane -> row w*32+it*8+(lane>>3), global chunk (lane&7)^(row&7)
  const unsigned short* agp[4];
  const unsigned short* bgp[4];
  unsigned short* lA[4];
  unsigned short* lB[4];
  #pragma unroll
  for (int it = 0; it < 4; it++){
    int r = w * 32 + it * 8 + (lane >> 3);
    int g = (lane & 7) ^ (r & 7);
    int grow = mt * BM + r;
    int cr   = grow < m ? grow : (m - 1);
    int tok  = tok_of_row[base + cr];
    agp[it] = xbf + (size_t)tok * CDIM + g * 8;
    bgp[it] = bsrc + (size_t)r * CDIM + g * 8;
    lA[it]  = &As[(w * 32 + it * 8) * BK];
    lB[it]  = &Bs[(w * 32 + it * 8) * BK];
  }

  floatx4 acc[4][4];
  #pragma unroll
  for (int i = 0; i < 4; i++)
    #pragma unroll
    for (int j = 0; j < 4; j++) acc[i][j] = (floatx4){0.f, 0.f, 0.f, 0.f};

  for (int kb = 0; kb < CDIM; kb += BK){
    #pragma unroll
    for (int it = 0; it < 4; it++) gld16(agp[it] + kb, lA[it]);
    #pragma unroll
    for (int it = 0; it < 4; it++) gld16(bgp[it] + kb, lB[it]);
    __syncthreads();
    #pragma unroll
    for (int ks = 0; ks < BK; ks += 32){
      const int cb = ks >> 3;
      short8 a[4], b[4];
      #pragma unroll
      for (int i = 0; i < 4; i++)
        a[i] = *(const short8*)&As[(wm * 64 + i * 16 + l16) * BK + (((q + cb) ^ sw) * 8)];
      #pragma unroll
      for (int j = 0; j < 4; j++)
        b[j] = *(const short8*)&Bs[(wn * 64 + j * 16 + l16) * BK + (((q + cb) ^ sw) * 8)];
      #pragma unroll
      for (int i = 0; i < 4; i++)
        #pragma unroll
        for (int j = 0; j < 4; j++)
          acc[i][j] = __builtin_amdgcn_mfma_f32_16x16x32_bf16(a[i], b[j], acc[i][j], 0, 0, 0);
    }
    __syncthreads();
  }

  #pragma unroll
  for (int i = 0; i < 4; i++){
    #pragma unroll
    for (int r = 0; r < 4; r++){
      int row  = wm * 64 + i * 16 + q * 4 + r;
      int grow = mt * BM + row;
      if (grow < m){
        size_t hrow = (size_t)(base + grow) * HP + (size_t)nt * BN;
        #pragma unroll
        for (int j = 0; j < 4; j++){
          float gv = gelu_tanh(acc[i][j][r]);
          hbuf[hrow + wn * 64 + j * 16 + l16] = f2bf(gv);
        }
      }
    }
  }
}

// ---- GEMM2: out[token] += gate * (hbuf_slice @ w2t_slice^T), K=HP, fp32 atomics ----
__global__ __launch_bounds__(256, 2)
void gemm2_expert(const unsigned short* __restrict__ hbuf,   // (ROWS, HP) bf16
                  const unsigned short* __restrict__ w2t,    // (E, C, HP) bf16
                  const int* __restrict__ cnt, const int* __restrict__ off,
                  const int* __restrict__ tok_of_row, const float* __restrict__ gate_of_row,
                  float* __restrict__ out,                   // (N_TOK, C) fp32
                  int HP){
  const int e  = blockIdx.z;
  const int m  = cnt[e];
  const int mt = blockIdx.y;
  if (mt * BM >= m) return;
  const int nt   = blockIdx.x;
  const int base = off[e];

  __shared__ __align__(16) unsigned short As[BM * BK];
  __shared__ __align__(16) unsigned short Bs[BN * BK];

  const int tid = threadIdx.x;
  const int lane = tid & 63, w = tid >> 6;
  const int wm = w & 1, wn = w >> 1;
  const int q = lane >> 4, l16 = lane & 15;
  const int sw = l16 & 7;

  const unsigned short* bsrc = w2t + ((size_t)e * CDIM + (size_t)nt * BN) * HP;

  const unsigned short* agp[4];
  const unsigned short* bgp[4];
  unsigned short* lA[4];
  unsigned short* lB[4];
  #pragma unroll
  for (int it = 0; it < 4; it++){
    int r = w * 32 + it * 8 + (lane >> 3);
    int g = (lane & 7) ^ (r & 7);
    int grow = mt * BM + r;
    int cr   = grow < m ? grow : (m - 1);
    agp[it] = hbuf + (size_t)(base + cr) * HP + g * 8;
    bgp[it] = bsrc + (size_t)r * HP + g * 8;
    lA[it]  = &As[(w * 32 + it * 8) * BK];
    lB[it]  = &Bs[(w * 32 + it * 8) * BK];
  }

  floatx4 acc[4][4];
  #pragma unroll
  for (int i = 0; i < 4; i++)
    #pragma unroll
    for (int j = 0; j < 4; j++) acc[i][j] = (floatx4){0.f, 0.f, 0.f, 0.f};

  for (int kb = 0; kb < HP; kb += BK){
    #pragma unroll
    for (int it = 0; it < 4; it++) gld16(agp[it] + kb, lA[it]);
    #pragma unroll
    for (int it = 0; it < 4; it++) gld16(bgp[it] + kb, lB[it]);
    __syncthreads();
    #pragma unroll
    for (int ks = 0; ks < BK; ks += 32){
      const int cb = ks >> 3;
      short8 a[4], b[4];
      #pragma unroll
      for (int i = 0; i < 4; i++)
        a[i] = *(const short8*)&As[(wm * 64 + i * 16 + l16) * BK + (((q + cb) ^ sw) * 8)];
      #pragma unroll
      for (int j = 0; j < 4; j++)
        b[j] = *(const short8*)&Bs[(wn * 64 + j * 16 + l16) * BK + (((q + cb) ^ sw) * 8)];
      #pragma unroll
      for (int i = 0; i < 4; i++)
        #pragma unroll
        for (int j = 0; j < 4; j++)
          acc[i][j] = __builtin_amdgcn_mfma_f32_16x16x32_bf16(a[i], b[j], acc[i][j], 0, 0, 0);
    }
    __syncthreads();
  }

  #pragma unroll
  for (int i = 0; i < 4; i++){
    #pragma unroll
    for (int r = 0; r < 4; r++){
      int row  = wm * 64 + i * 16 + q * 4 + r;
      int grow = mt * BM + row;
      if (grow < m){
        int gr = base + grow;
        int tok = tok_of_row[gr];
        float gate = gate_of_row[gr];
        float* orow = out + (size_t)tok * CDIM + (size_t)nt * BN;
        #pragma unroll
        for (int j = 0; j < 4; j++)
          atomicAdd(&orow[wn * 64 + j * 16 + l16], acc[i][j][r] * gate);
      }
    }
  }
}

extern "C" void kernel_launch(void* const* d_in, const int* in_sizes, int n_in,
                              void* d_out, int out_size, void* d_ws, size_t ws_size,
                              hipStream_t stream) {
  const float* x  = (const float*)d_in[0];
  const float* Wr = (const float*)d_in[1];
  const float* W1 = (const float*)d_in[2];
  const float* W2 = (const float*)d_in[3];
  float* out = (float*)d_out;

  hipMemsetAsync(out, 0, (size_t)N_TOK * CDIM * sizeof(float), stream);

  // ---- ws layout: meta (1 MB) + xbf (16 MB) + hbuf slice + weight slice ----
  const size_t META_SZ = 1u << 20;
  const size_t XBF_SZ  = (size_t)N_TOK * CDIM * 2;
  int P = -1;
  for (int cand = 1; cand <= 32; cand <<= 1){
    int HPc = HDIM / cand;
    size_t need = META_SZ + XBF_SZ
                + (size_t)ROWS * HPc * 2                 // hbuf slice (bf16)
                + (size_t)NEXP * HPc * CDIM * 2;         // weight slice (bf16)
    if (need <= ws_size){ P = cand; break; }
  }
  if (P < 0) return;  // ws too small for any plan: leave zeros (diagnostic)
  const int HP = HDIM / P;

  char* ws = (char*)d_ws;
  int*   cnt         = (int*)ws;
  int*   off         = cnt + 8;
  int*   cursor      = off + 8;
  int*   tok_of_row  = (int*)(ws + 1024);
  float* gate_of_row = (float*)(ws + 1024 + 65536);
  int*   top_e       = (int*)(ws + 1024 + 131072);
  float* top_g       = (float*)(ws + 1024 + 196608);

  unsigned short* xbf  = (unsigned short*)(ws + META_SZ);
  unsigned short* hbuf = (unsigned short*)(ws + META_SZ + XBF_SZ);
  unsigned short* wreg = (unsigned short*)(ws + META_SZ + XBF_SZ + (size_t)ROWS * HP * 2);

  hipMemsetAsync(cnt, 0, 96, stream);

  cast_x<<<dim3(N_TOK*CDIM/4/256), 256, 0, stream>>>((const float4*)x, (uint2*)xbf);
  router_topk<<<dim3(N_TOK/4), 256, 0, stream>>>(x, Wr, cnt, top_e, top_g);
  scan_offsets<<<1, 64, 0, stream>>>(cnt, off, cursor);
  assign_rows<<<dim3(N_TOK/256), 256, 0, stream>>>(off, cursor, top_e, top_g,
                                                   tok_of_row, gate_of_row);

  for (int p = 0; p < P; p++){
    const int h0 = p * HP;
    transpose_cast<<<dim3(HP/64, CDIM/64, NEXP), 256, 0, stream>>>(
        W1, wreg, /*roff=*/0, /*RP=*/CDIM, /*lds_=*/HDIM, /*coff=*/h0, /*CP=*/HP,
        (size_t)CDIM * HDIM);
    gemm1_expert<<<dim3(HP/BN, ROWS/BM, NEXP), 256, 0, stream>>>(
        xbf, wreg, cnt, off, tok_of_row, hbuf, HP);
    transpose_cast<<<dim3(CDIM/64, HP/64, NEXP), 256, 0, stream>>>(
        W2, wreg, /*roff=*/h0, /*RP=*/HP, /*lds_=*/CDIM, /*coff=*/0, /*CP=*/CDIM,
        (size_t)HDIM * CDIM);
    gemm2_expert<<<dim3(CDIM/BN, ROWS/BM, NEXP), 256, 0, stream>>>(
        hbuf, wreg, cnt, off, tok_of_row, gate_of_row, out, HP);
  }
}